// Round 10
// baseline (73.410 us; speedup 1.0000x reference)
//
#include <hip/hip_runtime.h>
#include <math.h>

#define IM 64
#define NBATCH 256
#define HID 64

typedef _Float16 f16;
typedef _Float16 f16x8 __attribute__((ext_vector_type(8)));
typedef _Float16 f16x2 __attribute__((ext_vector_type(2)));
typedef float    f32x4 __attribute__((ext_vector_type(4)));
typedef float    f32x2 __attribute__((ext_vector_type(2)));

// ws layout:
//  f16 [0,16384)      : MFMA A-frags. wt1 (idx<8192): k=32kh+8g+j (std);
//                       wt2: k=32kh+16(j>>2)+4g+(j&3) (perm = L1-acc layout)
//  f16 [16384,16640)  : w0h/b0h: pg*128 + c (w0), pg*128+64+c (b0)
//  f32 [8320,10368)   : scv[(b*2+s)*4] = {posx, posy, exp(lmr[pg]), b3[pg]}
//  f32 [10368,10752)  : b1 (128) | b2 (128) | w3 (128), pg-major (pg*64+c)
__global__ void prep_kernel(const float* __restrict__ w1,
                            const float* __restrict__ w2,
                            const float* __restrict__ w0,
                            const float* __restrict__ b0,
                            const float* __restrict__ b1,
                            const float* __restrict__ b2,
                            const float* __restrict__ w3,
                            const int*   __restrict__ shape_ids,
                            const float* __restrict__ raw_positions,
                            const float* __restrict__ lmr,
                            const float* __restrict__ b3,
                            f16* __restrict__ ws) {
    float* wsf = (float*)ws;
    int idx = blockIdx.x * 256 + threadIdx.x;
    if (idx < 16384) {
        int half = idx >> 13, r = idx & 8191;
        int j = r & 7, lane = (r >> 3) & 63, kh = (r >> 9) & 1;
        int mt = (r >> 10) & 3, pg = (r >> 12) & 1;
        int u = lane & 15, g = lane >> 4, n = 16*mt + u;
        int k; const float* w;
        if (half == 0) { k = 32*kh + 8*g + j;                 w = w1; }
        else           { k = 32*kh + 16*(j>>2) + 4*g + (j&3); w = w2; }
        ws[idx] = (f16)w[pg*4096 + k*64 + n];
    } else if (idx < 16640) {
        int r = idx - 16384, pg = r >> 7, q = r & 127;
        int c = q & 63;
        float v = (q < 64) ? w0[pg*64 + c] : b0[pg*64 + c];
        ws[idx] = (f16)v;
    } else if (idx < 18688) {
        int r = idx - 16640;                  // 0..2047, e = b*2+s
        int e = r >> 2, c = r & 3;
        float v;
        if (c == 0)      v = 1.f/(1.f + __expf(-raw_positions[e*2+0])) - 0.5f;
        else if (c == 1) v = 1.f/(1.f + __expf(-raw_positions[e*2+1])) - 0.5f;
        else if (c == 2) v = __expf(lmr[shape_ids[e]]);
        else             v = b3[shape_ids[e]];
        wsf[8320 + r] = v;
    } else if (idx < 19072) {
        int r = idx - 18688;                  // 0..383
        int seg = r >> 7, q = r & 127, pg = q >> 6, c = q & 63;
        const float* src = (seg == 0) ? b1 : (seg == 1) ? b2 : w3;
        wsf[10368 + r] = src[pg*64 + c];
    }
}

static __device__ __forceinline__ f16x2 cvt2(float a, float b) {
    return __builtin_bit_cast(f16x2, __builtin_amdgcn_cvt_pkrtz(a, b));
}
static __device__ __forceinline__ f32x2 pmax2(f32x2 v) {
    return __builtin_elementwise_max(v, (f32x2)0.f);
}
static __device__ __forceinline__ f16x2 hmax2(f16x2 v) {
    return __builtin_elementwise_max(v, (f16x2)(_Float16)0.f);
}
// minimax atan2, max err ~2e-7 rad
static __device__ __forceinline__ float fast_atan2(float y, float x) {
    float ax = fabsf(x), ay = fabsf(y);
    float mx = fmaxf(ax, ay), mn = fminf(ax, ay);
    float t = mn * __builtin_amdgcn_rcpf(mx);
    float z = t * t;
    float p = fmaf(z, -0.01172120f, 0.05265332f);
    p = fmaf(z, p, -0.11643287f);
    p = fmaf(z, p,  0.19354346f);
    p = fmaf(z, p, -0.33262347f);
    p = fmaf(z, p,  0.99997726f);
    float r = t * p;
    r = (ay > ax)  ? 1.5707964f - r : r;
    r = (x < 0.f)  ? 3.1415927f - r : r;
    return (y < 0.f) ? -r : r;
}

// One shape's full MLP chain for one image row. Fully unrolled, no LDS,
// no barriers -> two inlined calls form one scheduling region and the
// list scheduler interleaves the independent chains (latency hiding).
static __device__ __forceinline__ float shape_prob(
    const f16* __restrict__ ws, const float* __restrict__ wsf,
    int e /*b*2+s*/, int pg, int lane, int u, int g, float cx, float cy)
{
    const f32x4 scv = *(const f32x4*)&wsf[8320 + e*4];
    const float dx = cx - scv[0], dy = cy - scv[1];
    const float theta = fast_atan2(dy, dx);

    float th[4];
    #pragma unroll
    for (int nt = 0; nt < 4; ++nt) th[nt] = __shfl(theta, 16*nt + u);

    // ---- layer 0 (1->64): packed f16 straight into B-fragments
    f16x8 bf[4][2];
    {
        const f16* w0h = &ws[16384 + pg*128];
        f16x8 w0r[2], b0r[2];
        #pragma unroll
        for (int kh = 0; kh < 2; ++kh) {
            w0r[kh] = *(const f16x8*)&w0h[32*kh + 8*g];
            b0r[kh] = *(const f16x8*)&w0h[64 + 32*kh + 8*g];
        }
        #pragma unroll
        for (int nt = 0; nt < 4; ++nt) {
            const f16 thh = (f16)th[nt];
            const f16x2 th2 = {thh, thh};
            #pragma unroll
            for (int kh = 0; kh < 2; ++kh) {
                union { f16x2 h2[4]; f16x8 v8; } uu;
                union { f16x8 v8; f16x2 h2[4]; } wv, bv_;
                wv.v8 = w0r[kh]; bv_.v8 = b0r[kh];
                #pragma unroll
                for (int q = 0; q < 4; ++q)
                    uu.h2[q] = hmax2(__builtin_elementwise_fma(th2, wv.h2[q], bv_.h2[q]));
                bf[nt][kh] = uu.v8;
            }
        }
    }

    // ---- layer 1 + immediate repack (mt-paired: only 8 acc regs live)
    f16x8 cf[4][2];
    #pragma unroll
    for (int mp = 0; mp < 2; ++mp) {
        f32x4 acc[2][4];
        #pragma unroll
        for (int mh = 0; mh < 2; ++mh) {
            const int mt = 2*mp + mh;
            const f16x8 wf0 = *(const f16x8*)&ws[(((pg*4+mt)*2+0)*64 + lane)*8];
            const f16x8 wf1 = *(const f16x8*)&ws[(((pg*4+mt)*2+1)*64 + lane)*8];
            const f32x4 bv  = *(const f32x4*)&wsf[10368 + pg*64 + 16*mt + 4*g];
            #pragma unroll
            for (int nt = 0; nt < 4; ++nt) {
                f32x4 a = __builtin_amdgcn_mfma_f32_16x16x32_f16(wf0, bf[nt][0], bv, 0,0,0);
                a = __builtin_amdgcn_mfma_f32_16x16x32_f16(wf1, bf[nt][1], a, 0,0,0);
                acc[mh][nt] = a;
            }
        }
        #pragma unroll
        for (int nt = 0; nt < 4; ++nt) {
            union { f16x2 h2[4]; f16x8 v8; } uu;
            #pragma unroll
            for (int hh = 0; hh < 2; ++hh) {
                const f32x4 av = acc[hh][nt];
                uu.h2[hh*2+0] = hmax2(cvt2(av[0], av[1]));
                uu.h2[hh*2+1] = hmax2(cvt2(av[2], av[3]));
            }
            cf[nt][mp] = uu.v8;
        }
    }

    // ---- layer 2 + head fused
    f32x2 hp2[4] = {{0.f,0.f},{0.f,0.f},{0.f,0.f},{0.f,0.f}};
    #pragma unroll
    for (int mt = 0; mt < 4; ++mt) {
        const f16x8 wf0 = *(const f16x8*)&ws[8192 + (((pg*4+mt)*2+0)*64 + lane)*8];
        const f16x8 wf1 = *(const f16x8*)&ws[8192 + (((pg*4+mt)*2+1)*64 + lane)*8];
        const f32x4 bv  = *(const f32x4*)&wsf[10368 + 128 + pg*64 + 16*mt + 4*g];
        const f32x4 w3v = *(const f32x4*)&wsf[10368 + 256 + pg*64 + 16*mt + 4*g];
        const f32x2 w301 = {w3v[0], w3v[1]}, w323 = {w3v[2], w3v[3]};
        #pragma unroll
        for (int nt = 0; nt < 4; ++nt) {
            f32x4 a = __builtin_amdgcn_mfma_f32_16x16x32_f16(wf0, cf[nt][0], bv, 0,0,0);
            a = __builtin_amdgcn_mfma_f32_16x16x32_f16(wf1, cf[nt][1], a, 0,0,0);
            f32x2 e01 = pmax2((f32x2){a[0], a[1]});
            f32x2 e23 = pmax2((f32x2){a[2], a[3]});
            hp2[nt] = e01*w301 + hp2[nt];
            hp2[nt] = e23*w323 + hp2[nt];
        }
    }
    float hp[4];
    #pragma unroll
    for (int nt = 0; nt < 4; ++nt) {
        hp[nt] = hp2[nt][0] + hp2[nt][1];
        hp[nt] += __shfl_xor(hp[nt], 16);
        hp[nt] += __shfl_xor(hp[nt], 32);
    }
    float ov = hp[0];
    if (g == 1) ov = hp[1];
    if (g == 2) ov = hp[2];
    if (g == 3) ov = hp[3];
    ov += scv[3];

    const float r2    = sqrtf(dx*dx + dy*dy);
    const float logit = scv[2] * (__expf(ov) - r2);
    return __builtin_amdgcn_rcpf(1.f + __expf(-logit));
}

// 4096 blocks x 4 waves; 1 (image,row) item per wave; both shapes always
// computed as two independent interleaved chains. NO LDS, NO barriers.
__global__ __launch_bounds__(256, 2) void genmodel_kernel(
    const int* __restrict__ program_id,
    const int* __restrict__ shape_ids,
    const f16* __restrict__ ws,
    float* __restrict__ out)
{
    const float* wsf = (const float*)ws;
    const int tid  = threadIdx.x;
    const int wave = tid >> 6;
    const int lane = tid & 63;
    const int u = lane & 15, g = lane >> 4;

    const int gi   = blockIdx.x * 4 + wave;   // row-item in [0,16384)
    const int b    = gi >> 6;
    const int irow = gi & 63;

    const float cx = -1.0f + (2.0f/63.0f)*(float)lane;
    const float cy = -1.0f + (2.0f/63.0f)*(float)irow;

    const int pg0 = __builtin_amdgcn_readfirstlane(shape_ids[b*2 + 0]);
    const int pg1 = __builtin_amdgcn_readfirstlane(shape_ids[b*2 + 1]);

    const float p0 = shape_prob(ws, wsf, b*2 + 0, pg0, lane, u, g, cx, cy);
    const float p1 = shape_prob(ws, wsf, b*2 + 1, pg1, lane, u, g, cx, cy);

    const int pid = __builtin_amdgcn_readfirstlane(program_id[b]);
    float res;
    if (pid == 0) {
        res = p0;
    } else {
        float c = (pid == 2) ? (p0 - p1) : (p0 + p1);
        res = fminf(fmaxf(c, 0.f), 1.f);
    }
    out[b*(IM*IM) + irow*64 + lane] = res;
}

extern "C" void kernel_launch(void* const* d_in, const int* in_sizes, int n_in,
                              void* d_out, int out_size, void* d_ws, size_t ws_size,
                              hipStream_t stream) {
    const int*   program_id    = (const int*)  d_in[0];
    const int*   shape_ids     = (const int*)  d_in[1];
    const float* raw_positions = (const float*)d_in[2];
    const float* w0            = (const float*)d_in[3];
    const float* b0            = (const float*)d_in[4];
    const float* w1            = (const float*)d_in[5];
    const float* b1            = (const float*)d_in[6];
    const float* w2            = (const float*)d_in[7];
    const float* b2            = (const float*)d_in[8];
    const float* w3            = (const float*)d_in[9];
    const float* b3            = (const float*)d_in[10];
    const float* lmr           = (const float*)d_in[11];
    float* out = (float*)d_out;
    f16*   ws  = (f16*)d_ws;                  // 43 KB used

    prep_kernel<<<75, 256, 0, stream>>>(w1, w2, w0, b0, b1, b2, w3,
                                        shape_ids, raw_positions, lmr, b3, ws);

    genmodel_kernel<<<NBATCH*16, 256, 0, stream>>>(program_id, shape_ids, ws, out);
}

// Round 11
// 66.695 us; speedup vs baseline: 1.1007x; 1.1007x over previous
//
#include <hip/hip_runtime.h>
#include <math.h>

#define IM 64
#define NBATCH 256
#define HID 64

typedef _Float16 f16;
typedef _Float16 f16x8 __attribute__((ext_vector_type(8)));
typedef _Float16 f16x2 __attribute__((ext_vector_type(2)));
typedef float    f32x4 __attribute__((ext_vector_type(4)));
typedef float    f32x2 __attribute__((ext_vector_type(2)));

// ws layout:
//  f16 [0,16384)      : MFMA A-frags. wt1 (idx<8192): k=32kh+8g+j (std);
//                       wt2: k=32kh+16(j>>2)+4g+(j&3) (perm = L1-acc layout)
//  f16 [16384,16640)  : w0h/b0h: pg*128 + c (w0), pg*128+64+c (b0)
//  f32 [8320,10368)   : scv[(b*2+s)*4] = {posx, posy, exp(lmr[pg]), b3[pg]}
//  f32 [10368,10752)  : b1 (128) | b2 (128) | w3 (128), pg-major (pg*64+c)
__global__ void prep_kernel(const float* __restrict__ w1,
                            const float* __restrict__ w2,
                            const float* __restrict__ w0,
                            const float* __restrict__ b0,
                            const float* __restrict__ b1,
                            const float* __restrict__ b2,
                            const float* __restrict__ w3,
                            const int*   __restrict__ shape_ids,
                            const float* __restrict__ raw_positions,
                            const float* __restrict__ lmr,
                            const float* __restrict__ b3,
                            f16* __restrict__ ws) {
    float* wsf = (float*)ws;
    int idx = blockIdx.x * 256 + threadIdx.x;
    if (idx < 16384) {
        int half = idx >> 13, r = idx & 8191;
        int j = r & 7, lane = (r >> 3) & 63, kh = (r >> 9) & 1;
        int mt = (r >> 10) & 3, pg = (r >> 12) & 1;
        int u = lane & 15, g = lane >> 4, n = 16*mt + u;
        int k; const float* w;
        if (half == 0) { k = 32*kh + 8*g + j;                 w = w1; }
        else           { k = 32*kh + 16*(j>>2) + 4*g + (j&3); w = w2; }
        ws[idx] = (f16)w[pg*4096 + k*64 + n];
    } else if (idx < 16640) {
        int r = idx - 16384, pg = r >> 7, q = r & 127;
        int c = q & 63;
        float v = (q < 64) ? w0[pg*64 + c] : b0[pg*64 + c];
        ws[idx] = (f16)v;
    } else if (idx < 18688) {
        int r = idx - 16640;                  // 0..2047, e = b*2+s
        int e = r >> 2, c = r & 3;
        float v;
        if (c == 0)      v = 1.f/(1.f + __expf(-raw_positions[e*2+0])) - 0.5f;
        else if (c == 1) v = 1.f/(1.f + __expf(-raw_positions[e*2+1])) - 0.5f;
        else if (c == 2) v = __expf(lmr[shape_ids[e]]);
        else             v = b3[shape_ids[e]];
        wsf[8320 + r] = v;
    } else if (idx < 19072) {
        int r = idx - 18688;                  // 0..383
        int seg = r >> 7, q = r & 127, pg = q >> 6, c = q & 63;
        const float* src = (seg == 0) ? b1 : (seg == 1) ? b2 : w3;
        wsf[10368 + r] = src[pg*64 + c];
    }
}

static __device__ __forceinline__ f16x2 cvt2(float a, float b) {
    return __builtin_bit_cast(f16x2, __builtin_amdgcn_cvt_pkrtz(a, b));
}
static __device__ __forceinline__ f32x2 pmax2(f32x2 v) {
    return __builtin_elementwise_max(v, (f32x2)0.f);
}
static __device__ __forceinline__ f16x2 hmax2(f16x2 v) {
    return __builtin_elementwise_max(v, (f16x2)(_Float16)0.f);
}
// minimax atan2, max err ~2e-7 rad
static __device__ __forceinline__ float fast_atan2(float y, float x) {
    float ax = fabsf(x), ay = fabsf(y);
    float mx = fmaxf(ax, ay), mn = fminf(ax, ay);
    float t = mn * __builtin_amdgcn_rcpf(mx);
    float z = t * t;
    float p = fmaf(z, -0.01172120f, 0.05265332f);
    p = fmaf(z, p, -0.11643287f);
    p = fmaf(z, p,  0.19354346f);
    p = fmaf(z, p, -0.33262347f);
    p = fmaf(z, p,  0.99997726f);
    float r = t * p;
    r = (ay > ax)  ? 1.5707964f - r : r;
    r = (x < 0.f)  ? 3.1415927f - r : r;
    return (y < 0.f) ? -r : r;
}

// One shape's full MLP chain for one image row. ALL weight fragments are
// prefetched into registers up-front (R10 lesson: mt-loop loads at short
// load->use distance exposed ~7k cycles of serial L2 latency per shape;
// grouping the independent loads exposes it once). VGPR-rich by design -
// we never got >2.6 waves/SIMD anyway, so spend registers on ILP.
static __device__ __forceinline__ float shape_prob(
    const f16* __restrict__ ws, const float* __restrict__ wsf,
    int e /*b*2+s*/, int pg, int lane, int u, int g, float cx, float cy)
{
    const f32x4 scv = *(const f32x4*)&wsf[8320 + e*4];

    // ---- prefetch group 1: L1 A-frags, L0 weights, L1 bias
    f16x8 wfA[4][2];
    #pragma unroll
    for (int mt = 0; mt < 4; ++mt)
        #pragma unroll
        for (int kh = 0; kh < 2; ++kh)
            wfA[mt][kh] = *(const f16x8*)&ws[(((pg*4+mt)*2+kh)*64 + lane)*8];
    f16x8 w0r[2], b0r[2];
    #pragma unroll
    for (int kh = 0; kh < 2; ++kh) {
        const f16* w0h = &ws[16384 + pg*128];
        w0r[kh] = *(const f16x8*)&w0h[32*kh + 8*g];
        b0r[kh] = *(const f16x8*)&w0h[64 + 32*kh + 8*g];
    }
    f32x4 bv1[4];
    #pragma unroll
    for (int mt = 0; mt < 4; ++mt)
        bv1[mt] = *(const f32x4*)&wsf[10368 + pg*64 + 16*mt + 4*g];

    // ---- theta path (VALU) overlaps the loads above
    const float dx = cx - scv[0], dy = cy - scv[1];
    const float theta = fast_atan2(dy, dx);
    float th[4];
    #pragma unroll
    for (int nt = 0; nt < 4; ++nt) th[nt] = __shfl(theta, 16*nt + u);

    // ---- prefetch group 2: L2 A-frags, L2/head biases (issue now, used late)
    f16x8 wfB[4][2];
    #pragma unroll
    for (int mt = 0; mt < 4; ++mt)
        #pragma unroll
        for (int kh = 0; kh < 2; ++kh)
            wfB[mt][kh] = *(const f16x8*)&ws[8192 + (((pg*4+mt)*2+kh)*64 + lane)*8];
    f32x4 bv2[4], w3v[4];
    #pragma unroll
    for (int mt = 0; mt < 4; ++mt) {
        bv2[mt] = *(const f32x4*)&wsf[10368 + 128 + pg*64 + 16*mt + 4*g];
        w3v[mt] = *(const f32x4*)&wsf[10368 + 256 + pg*64 + 16*mt + 4*g];
    }

    // ---- layer 0 (1->64): packed f16 straight into B-fragments
    f16x8 bf[4][2];
    #pragma unroll
    for (int nt = 0; nt < 4; ++nt) {
        const f16 thh = (f16)th[nt];
        const f16x2 th2 = {thh, thh};
        #pragma unroll
        for (int kh = 0; kh < 2; ++kh) {
            union { f16x2 h2[4]; f16x8 v8; } uu;
            union { f16x8 v8; f16x2 h2[4]; } wv, bv_;
            wv.v8 = w0r[kh]; bv_.v8 = b0r[kh];
            #pragma unroll
            for (int q = 0; q < 4; ++q)
                uu.h2[q] = hmax2(__builtin_elementwise_fma(th2, wv.h2[q], bv_.h2[q]));
            bf[nt][kh] = uu.v8;
        }
    }

    // ---- layer 1 + immediate repack (mt-paired: only 8 acc regs live)
    f16x8 cf[4][2];
    #pragma unroll
    for (int mp = 0; mp < 2; ++mp) {
        f32x4 acc[2][4];
        #pragma unroll
        for (int mh = 0; mh < 2; ++mh) {
            const int mt = 2*mp + mh;
            #pragma unroll
            for (int nt = 0; nt < 4; ++nt) {
                f32x4 a = __builtin_amdgcn_mfma_f32_16x16x32_f16(wfA[mt][0], bf[nt][0], bv1[mt], 0,0,0);
                a = __builtin_amdgcn_mfma_f32_16x16x32_f16(wfA[mt][1], bf[nt][1], a, 0,0,0);
                acc[mh][nt] = a;
            }
        }
        #pragma unroll
        for (int nt = 0; nt < 4; ++nt) {
            union { f16x2 h2[4]; f16x8 v8; } uu;
            #pragma unroll
            for (int hh = 0; hh < 2; ++hh) {
                const f32x4 av = acc[hh][nt];
                uu.h2[hh*2+0] = hmax2(cvt2(av[0], av[1]));
                uu.h2[hh*2+1] = hmax2(cvt2(av[2], av[3]));
            }
            cf[nt][mp] = uu.v8;
        }
    }

    // ---- layer 2 + head fused
    f32x2 hp2[4] = {{0.f,0.f},{0.f,0.f},{0.f,0.f},{0.f,0.f}};
    #pragma unroll
    for (int mt = 0; mt < 4; ++mt) {
        const f32x2 w301 = {w3v[mt][0], w3v[mt][1]}, w323 = {w3v[mt][2], w3v[mt][3]};
        #pragma unroll
        for (int nt = 0; nt < 4; ++nt) {
            f32x4 a = __builtin_amdgcn_mfma_f32_16x16x32_f16(wfB[mt][0], cf[nt][0], bv2[mt], 0,0,0);
            a = __builtin_amdgcn_mfma_f32_16x16x32_f16(wfB[mt][1], cf[nt][1], a, 0,0,0);
            f32x2 e01 = pmax2((f32x2){a[0], a[1]});
            f32x2 e23 = pmax2((f32x2){a[2], a[3]});
            hp2[nt] = e01*w301 + hp2[nt];
            hp2[nt] = e23*w323 + hp2[nt];
        }
    }
    float hp[4];
    #pragma unroll
    for (int nt = 0; nt < 4; ++nt) {
        hp[nt] = hp2[nt][0] + hp2[nt][1];
        hp[nt] += __shfl_xor(hp[nt], 16);
        hp[nt] += __shfl_xor(hp[nt], 32);
    }
    float ov = hp[0];
    if (g == 1) ov = hp[1];
    if (g == 2) ov = hp[2];
    if (g == 3) ov = hp[3];
    ov += scv[3];

    const float r2    = sqrtf(dx*dx + dy*dy);
    const float logit = scv[2] * (__expf(ov) - r2);
    return __builtin_amdgcn_rcpf(1.f + __expf(-logit));
}

// 4096 blocks x 4 waves; 1 (image,row) item per wave; both shapes always
// computed. NO LDS, NO barriers.
__global__ __launch_bounds__(256, 2) void genmodel_kernel(
    const int* __restrict__ program_id,
    const int* __restrict__ shape_ids,
    const f16* __restrict__ ws,
    float* __restrict__ out)
{
    const float* wsf = (const float*)ws;
    const int tid  = threadIdx.x;
    const int wave = tid >> 6;
    const int lane = tid & 63;
    const int u = lane & 15, g = lane >> 4;

    const int gi   = blockIdx.x * 4 + wave;   // row-item in [0,16384)
    const int b    = gi >> 6;
    const int irow = gi & 63;

    const float cx = -1.0f + (2.0f/63.0f)*(float)lane;
    const float cy = -1.0f + (2.0f/63.0f)*(float)irow;

    const int pg0 = __builtin_amdgcn_readfirstlane(shape_ids[b*2 + 0]);
    const int pg1 = __builtin_amdgcn_readfirstlane(shape_ids[b*2 + 1]);

    const float p0 = shape_prob(ws, wsf, b*2 + 0, pg0, lane, u, g, cx, cy);
    const float p1 = shape_prob(ws, wsf, b*2 + 1, pg1, lane, u, g, cx, cy);

    const int pid = __builtin_amdgcn_readfirstlane(program_id[b]);
    float res;
    if (pid == 0) {
        res = p0;
    } else {
        float c = (pid == 2) ? (p0 - p1) : (p0 + p1);
        res = fminf(fmaxf(c, 0.f), 1.f);
    }
    out[b*(IM*IM) + irow*64 + lane] = res;
}

extern "C" void kernel_launch(void* const* d_in, const int* in_sizes, int n_in,
                              void* d_out, int out_size, void* d_ws, size_t ws_size,
                              hipStream_t stream) {
    const int*   program_id    = (const int*)  d_in[0];
    const int*   shape_ids     = (const int*)  d_in[1];
    const float* raw_positions = (const float*)d_in[2];
    const float* w0            = (const float*)d_in[3];
    const float* b0            = (const float*)d_in[4];
    const float* w1            = (const float*)d_in[5];
    const float* b1            = (const float*)d_in[6];
    const float* w2            = (const float*)d_in[7];
    const float* b2            = (const float*)d_in[8];
    const float* w3            = (const float*)d_in[9];
    const float* b3            = (const float*)d_in[10];
    const float* lmr           = (const float*)d_in[11];
    float* out = (float*)d_out;
    f16*   ws  = (f16*)d_ws;                  // 43 KB used

    prep_kernel<<<75, 256, 0, stream>>>(w1, w2, w0, b0, b1, b2, w3,
                                        shape_ids, raw_positions, lmr, b3, ws);

    genmodel_kernel<<<NBATCH*16, 256, 0, stream>>>(program_id, shape_ids, ws, out);
}

// Round 12
// 28.257 us; speedup vs baseline: 2.5979x; 2.3603x over previous
//
#include <hip/hip_runtime.h>
#include <math.h>

#define IM 64
#define NBATCH 256
#define HID 64
#define TT 2048                 // table samples per program
#define PI_F 3.14159265358979f

typedef _Float16 f16;
typedef _Float16 f16x8 __attribute__((ext_vector_type(8)));
typedef _Float16 f16x2 __attribute__((ext_vector_type(2)));
typedef float    f32x4 __attribute__((ext_vector_type(4)));
typedef float    f32x2 __attribute__((ext_vector_type(2)));

// ws layout:
//  f16 [0,16384)      : MFMA A-frags. wt1 (idx<8192): k=32kh+8g+j (std);
//                       wt2: k=32kh+16(j>>2)+4g+(j&3) (perm = L1-acc layout)
//  f16 [16384,16640)  : w0h/b0h: pg*128 + c (w0), pg*128+64+c (b0)
//  f32 [8320,10368)   : scv[(b*2+s)*4] = {posx, posy, exp(lmr[pg]), (float)pg}
//  f32 [10368,10752)  : b1 (128) | b2 (128) | w3 (128), pg-major (pg*64+c)
//  f32 [10752,14848)  : tab[pg*TT + i] = o_pg(theta_i) + b3[pg]
__global__ void prep_kernel(const float* __restrict__ w1,
                            const float* __restrict__ w2,
                            const float* __restrict__ w0,
                            const float* __restrict__ b0,
                            const float* __restrict__ b1,
                            const float* __restrict__ b2,
                            const float* __restrict__ w3,
                            const int*   __restrict__ shape_ids,
                            const float* __restrict__ raw_positions,
                            const float* __restrict__ lmr,
                            f16* __restrict__ ws) {
    float* wsf = (float*)ws;
    int idx = blockIdx.x * 256 + threadIdx.x;
    if (idx < 16384) {
        int half = idx >> 13, r = idx & 8191;
        int j = r & 7, lane = (r >> 3) & 63, kh = (r >> 9) & 1;
        int mt = (r >> 10) & 3, pg = (r >> 12) & 1;
        int u = lane & 15, g = lane >> 4, n = 16*mt + u;
        int k; const float* w;
        if (half == 0) { k = 32*kh + 8*g + j;                 w = w1; }
        else           { k = 32*kh + 16*(j>>2) + 4*g + (j&3); w = w2; }
        ws[idx] = (f16)w[pg*4096 + k*64 + n];
    } else if (idx < 16640) {
        int r = idx - 16384, pg = r >> 7, q = r & 127;
        int c = q & 63;
        float v = (q < 64) ? w0[pg*64 + c] : b0[pg*64 + c];
        ws[idx] = (f16)v;
    } else if (idx < 18688) {
        int r = idx - 16640;                  // 0..2047, e = b*2+s
        int e = r >> 2, c = r & 3;
        float v;
        if (c == 0)      v = 1.f/(1.f + __expf(-raw_positions[e*2+0])) - 0.5f;
        else if (c == 1) v = 1.f/(1.f + __expf(-raw_positions[e*2+1])) - 0.5f;
        else if (c == 2) v = __expf(lmr[shape_ids[e]]);
        else             v = (float)shape_ids[e];
        wsf[8320 + r] = v;
    } else if (idx < 19072) {
        int r = idx - 18688;                  // 0..383
        int seg = r >> 7, q = r & 127, pg = q >> 6, c = q & 63;
        const float* src = (seg == 0) ? b1 : (seg == 1) ? b2 : w3;
        wsf[10368 + r] = src[pg*64 + c];
    }
}

static __device__ __forceinline__ f16x2 cvt2(float a, float b) {
    return __builtin_bit_cast(f16x2, __builtin_amdgcn_cvt_pkrtz(a, b));
}
static __device__ __forceinline__ f32x2 pmax2(f32x2 v) {
    return __builtin_elementwise_max(v, (f32x2)0.f);
}
static __device__ __forceinline__ f16x2 hmax2(f16x2 v) {
    return __builtin_elementwise_max(v, (f16x2)(_Float16)0.f);
}
// minimax atan2, max err ~2e-7 rad
static __device__ __forceinline__ float fast_atan2(float y, float x) {
    float ax = fabsf(x), ay = fabsf(y);
    float mx = fmaxf(ax, ay), mn = fminf(ax, ay);
    float t = mn * __builtin_amdgcn_rcpf(mx);
    float z = t * t;
    float p = fmaf(z, -0.01172120f, 0.05265332f);
    p = fmaf(z, p, -0.11643287f);
    p = fmaf(z, p,  0.19354346f);
    p = fmaf(z, p, -0.33262347f);
    p = fmaf(z, p,  0.99997726f);
    float r = t * p;
    r = (ay > ax)  ? 1.5707964f - r : r;
    r = (x < 0.f)  ? 3.1415927f - r : r;
    return (y < 0.f) ? -r : r;
}

// MLP head value ov for one wave of 64 thetas (lane's theta -> lane's ov).
// Same verified MFMA chain as R11 (prefetch-grouped).
static __device__ __forceinline__ float mlp_ov(
    const f16* __restrict__ ws, const float* __restrict__ wsf,
    int pg, int lane, int u, int g, float theta)
{
    // prefetch: L1/L2 A-frags, L0 weights, biases
    f16x8 wfA[4][2], wfB[4][2];
    #pragma unroll
    for (int mt = 0; mt < 4; ++mt)
        #pragma unroll
        for (int kh = 0; kh < 2; ++kh) {
            wfA[mt][kh] = *(const f16x8*)&ws[(((pg*4+mt)*2+kh)*64 + lane)*8];
            wfB[mt][kh] = *(const f16x8*)&ws[8192 + (((pg*4+mt)*2+kh)*64 + lane)*8];
        }
    f16x8 w0r[2], b0r[2];
    #pragma unroll
    for (int kh = 0; kh < 2; ++kh) {
        const f16* w0h = &ws[16384 + pg*128];
        w0r[kh] = *(const f16x8*)&w0h[32*kh + 8*g];
        b0r[kh] = *(const f16x8*)&w0h[64 + 32*kh + 8*g];
    }
    f32x4 bv1[4], bv2[4], w3v[4];
    #pragma unroll
    for (int mt = 0; mt < 4; ++mt) {
        bv1[mt] = *(const f32x4*)&wsf[10368 + pg*64 + 16*mt + 4*g];
        bv2[mt] = *(const f32x4*)&wsf[10368 + 128 + pg*64 + 16*mt + 4*g];
        w3v[mt] = *(const f32x4*)&wsf[10368 + 256 + pg*64 + 16*mt + 4*g];
    }

    float th[4];
    #pragma unroll
    for (int nt = 0; nt < 4; ++nt) th[nt] = __shfl(theta, 16*nt + u);

    // layer 0 -> B-fragments
    f16x8 bf[4][2];
    #pragma unroll
    for (int nt = 0; nt < 4; ++nt) {
        const f16 thh = (f16)th[nt];
        const f16x2 th2 = {thh, thh};
        #pragma unroll
        for (int kh = 0; kh < 2; ++kh) {
            union { f16x2 h2[4]; f16x8 v8; } uu;
            union { f16x8 v8; f16x2 h2[4]; } wv, bv_;
            wv.v8 = w0r[kh]; bv_.v8 = b0r[kh];
            #pragma unroll
            for (int q = 0; q < 4; ++q)
                uu.h2[q] = hmax2(__builtin_elementwise_fma(th2, wv.h2[q], bv_.h2[q]));
            bf[nt][kh] = uu.v8;
        }
    }

    // layer 1 + in-lane repack
    f16x8 cf[4][2];
    #pragma unroll
    for (int mp = 0; mp < 2; ++mp) {
        f32x4 acc[2][4];
        #pragma unroll
        for (int mh = 0; mh < 2; ++mh) {
            const int mt = 2*mp + mh;
            #pragma unroll
            for (int nt = 0; nt < 4; ++nt) {
                f32x4 a = __builtin_amdgcn_mfma_f32_16x16x32_f16(wfA[mt][0], bf[nt][0], bv1[mt], 0,0,0);
                a = __builtin_amdgcn_mfma_f32_16x16x32_f16(wfA[mt][1], bf[nt][1], a, 0,0,0);
                acc[mh][nt] = a;
            }
        }
        #pragma unroll
        for (int nt = 0; nt < 4; ++nt) {
            union { f16x2 h2[4]; f16x8 v8; } uu;
            #pragma unroll
            for (int hh = 0; hh < 2; ++hh) {
                const f32x4 av = acc[hh][nt];
                uu.h2[hh*2+0] = hmax2(cvt2(av[0], av[1]));
                uu.h2[hh*2+1] = hmax2(cvt2(av[2], av[3]));
            }
            cf[nt][mp] = uu.v8;
        }
    }

    // layer 2 + head
    f32x2 hp2[4] = {{0.f,0.f},{0.f,0.f},{0.f,0.f},{0.f,0.f}};
    #pragma unroll
    for (int mt = 0; mt < 4; ++mt) {
        const f32x2 w301 = {w3v[mt][0], w3v[mt][1]}, w323 = {w3v[mt][2], w3v[mt][3]};
        #pragma unroll
        for (int nt = 0; nt < 4; ++nt) {
            f32x4 a = __builtin_amdgcn_mfma_f32_16x16x32_f16(wfB[mt][0], cf[nt][0], bv2[mt], 0,0,0);
            a = __builtin_amdgcn_mfma_f32_16x16x32_f16(wfB[mt][1], cf[nt][1], a, 0,0,0);
            f32x2 e01 = pmax2((f32x2){a[0], a[1]});
            f32x2 e23 = pmax2((f32x2){a[2], a[3]});
            hp2[nt] = e01*w301 + hp2[nt];
            hp2[nt] = e23*w323 + hp2[nt];
        }
    }
    float hp[4];
    #pragma unroll
    for (int nt = 0; nt < 4; ++nt) {
        hp[nt] = hp2[nt][0] + hp2[nt][1];
        hp[nt] += __shfl_xor(hp[nt], 16);
        hp[nt] += __shfl_xor(hp[nt], 32);
    }
    float ov = hp[0];
    if (g == 1) ov = hp[1];
    if (g == 2) ov = hp[2];
    if (g == 3) ov = hp[3];
    return ov;
}

// Tabulation: 64 blocks x 1 wave; block gi covers samples (gi&31)*64..+63 of
// program pg=gi>>5. tab[pg*TT+i] = o_pg(theta_i) + b3[pg].
__global__ __launch_bounds__(64, 2) void tab_kernel(
    const f16* __restrict__ ws, const float* __restrict__ b3,
    float* __restrict__ tab)
{
    const float* wsf = (const float*)ws;
    const int lane = threadIdx.x;
    const int u = lane & 15, g = lane >> 4;
    const int gi = blockIdx.x;                // [0,64)
    const int pg = gi >> 5;
    const int i0 = (gi & 31)*64 + lane;       // sample index [0,TT)
    const float theta = -PI_F + (2.0f*PI_F/(float)(TT-1)) * (float)i0;
    const float ov = mlp_ov(ws, wsf, pg, lane, u, g, theta);
    tab[pg*TT + i0] = ov + b3[pg];
}

// Render: 1 thread = 1 pixel. theta -> table lerp -> logit -> sigmoid.
__global__ void render_kernel(const int* __restrict__ program_id,
                              const f16* __restrict__ ws,
                              float* __restrict__ out)
{
    const float* wsf = (const float*)ws;
    const float* tab = wsf + 10752;
    const int gi = blockIdx.x * 256 + threadIdx.x;   // [0, 1M)
    const int b   = gi >> 12;
    const int px  = gi & 4095;
    const int row = px >> 6, col = px & 63;
    const float cx = -1.f + (2.f/63.f)*(float)col;
    const float cy = -1.f + (2.f/63.f)*(float)row;

    float p01[2];
    #pragma unroll
    for (int s = 0; s < 2; ++s) {
        const f32x4 scv = *(const f32x4*)&wsf[8320 + (b*2 + s)*4];
        const float dx = cx - scv[0], dy = cy - scv[1];
        const float theta = fast_atan2(dy, dx);
        const float r2 = sqrtf(dx*dx + dy*dy);
        float x = (theta + PI_F) * ((float)(TT-1)/(2.f*PI_F));
        x = fminf(fmaxf(x, 0.f), (float)(TT-1));
        const float fi = floorf(fminf(x, (float)(TT-2)));
        const int   i  = (int)fi;
        const float f  = x - fi;
        const float* tb = tab + ((int)scv[3])*TT;
        const float t0 = tb[i], t1 = tb[i+1];
        const float o  = fmaf(f, t1 - t0, t0);
        const float logit = scv[2] * (__expf(o) - r2);
        p01[s] = __builtin_amdgcn_rcpf(1.f + __expf(-logit));
    }

    const int pid = program_id[b];
    float res;
    if (pid == 0) {
        res = p01[0];
    } else {
        float c = (pid == 2) ? (p01[0] - p01[1]) : (p01[0] + p01[1]);
        res = fminf(fmaxf(c, 0.f), 1.f);
    }
    out[gi] = res;
}

extern "C" void kernel_launch(void* const* d_in, const int* in_sizes, int n_in,
                              void* d_out, int out_size, void* d_ws, size_t ws_size,
                              hipStream_t stream) {
    const int*   program_id    = (const int*)  d_in[0];
    const int*   shape_ids     = (const int*)  d_in[1];
    const float* raw_positions = (const float*)d_in[2];
    const float* w0            = (const float*)d_in[3];
    const float* b0            = (const float*)d_in[4];
    const float* w1            = (const float*)d_in[5];
    const float* b1            = (const float*)d_in[6];
    const float* w2            = (const float*)d_in[7];
    const float* b2            = (const float*)d_in[8];
    const float* w3            = (const float*)d_in[9];
    const float* b3            = (const float*)d_in[10];
    const float* lmr           = (const float*)d_in[11];
    float* out = (float*)d_out;
    f16*   ws  = (f16*)d_ws;                  // ~58 KB used
    float* tab = (float*)d_ws + 10752;

    prep_kernel<<<75, 256, 0, stream>>>(w1, w2, w0, b0, b1, b2, w3,
                                        shape_ids, raw_positions, lmr, ws);

    tab_kernel<<<64, 64, 0, stream>>>(ws, b3, tab);

    render_kernel<<<4096, 256, 0, stream>>>(program_id, ws, out);
}

// Round 13
// 18.293 us; speedup vs baseline: 4.0130x; 1.5447x over previous
//
#include <hip/hip_runtime.h>
#include <math.h>

#define IM 64
#define NBATCH 256
#define HID 64
#define TT 2048                 // table samples per program
#define PI_F 3.14159265358979f

typedef _Float16 f16;
typedef _Float16 f16x8 __attribute__((ext_vector_type(8)));
typedef _Float16 f16x2 __attribute__((ext_vector_type(2)));
typedef float    f32x4 __attribute__((ext_vector_type(4)));
typedef float    f32x2 __attribute__((ext_vector_type(2)));

// ws (f32 view) layout:
//  [8320,10368)   : scv[(b*2+s)*4] = {posx, posy, exp(lmr[pg]), (float)pg}
//  [10752,14848)  : tab[pg*TT + i] = o_pg(theta_i) + b3[pg]

static __device__ __forceinline__ f16x2 cvt2(float a, float b) {
    return __builtin_bit_cast(f16x2, __builtin_amdgcn_cvt_pkrtz(a, b));
}
static __device__ __forceinline__ f32x2 pmax2(f32x2 v) {
    return __builtin_elementwise_max(v, (f32x2)0.f);
}
static __device__ __forceinline__ f16x2 hmax2(f16x2 v) {
    return __builtin_elementwise_max(v, (f16x2)(_Float16)0.f);
}
// minimax atan2, max err ~2e-7 rad
static __device__ __forceinline__ float fast_atan2(float y, float x) {
    float ax = fabsf(x), ay = fabsf(y);
    float mx = fmaxf(ax, ay), mn = fminf(ax, ay);
    float t = mn * __builtin_amdgcn_rcpf(mx);
    float z = t * t;
    float p = fmaf(z, -0.01172120f, 0.05265332f);
    p = fmaf(z, p, -0.11643287f);
    p = fmaf(z, p,  0.19354346f);
    p = fmaf(z, p, -0.33262347f);
    p = fmaf(z, p,  0.99997726f);
    float r = t * p;
    r = (ay > ax)  ? 1.5707964f - r : r;
    r = (x < 0.f)  ? 3.1415927f - r : r;
    return (y < 0.f) ? -r : r;
}

// Single setup kernel: blocks 0..15 (4 waves each = 64 wave-chunks) tabulate
// o_pg(theta) via the MFMA chain, gathering weight fragments DIRECTLY from
// raw w1/w2/w0/b0 (independent loads, one latency exposure - no prep pass).
// Block 16 computes the per-(b,s) scalar table. One kernel = minimal serial
// prefix before render.
__global__ __launch_bounds__(256) void setup_kernel(
    const float* __restrict__ w0, const float* __restrict__ b0,
    const float* __restrict__ w1, const float* __restrict__ b1,
    const float* __restrict__ w2, const float* __restrict__ b2,
    const float* __restrict__ w3, const float* __restrict__ b3,
    const int*   __restrict__ shape_ids,
    const float* __restrict__ raw_positions,
    const float* __restrict__ lmr,
    float* __restrict__ wsf)
{
    const int tid = threadIdx.x;
    if (blockIdx.x >= 16) {
        // ---- scv table: 2048 floats
        #pragma unroll
        for (int rep = 0; rep < 8; ++rep) {
            int idx = rep*256 + tid;          // 0..2047
            int e = idx >> 2, c = idx & 3;
            float v;
            if (c == 0)      v = 1.f/(1.f + __expf(-raw_positions[e*2+0])) - 0.5f;
            else if (c == 1) v = 1.f/(1.f + __expf(-raw_positions[e*2+1])) - 0.5f;
            else if (c == 2) v = __expf(lmr[shape_ids[e]]);
            else             v = (float)shape_ids[e];
            wsf[8320 + idx] = v;
        }
        return;
    }

    const int wave = tid >> 6;
    const int lane = tid & 63;
    const int u = lane & 15, g = lane >> 4;
    const int chunk = blockIdx.x*4 + wave;    // [0,64)
    const int pg = chunk >> 5;
    const int i0 = (chunk & 31)*64 + lane;    // sample index [0,TT)
    const float theta = -PI_F + (2.0f*PI_F/(float)(TT-1)) * (float)i0;

    // ---- gather all fragments from raw weights (independent loads)
    f16x8 wfA[4][2], wfB[4][2];
    #pragma unroll
    for (int mt = 0; mt < 4; ++mt)
        #pragma unroll
        for (int kh = 0; kh < 2; ++kh) {
            f16x8 a, bq;
            #pragma unroll
            for (int j = 0; j < 8; ++j) {
                const int k1 = 32*kh + 8*g + j;                  // std order
                const int k2 = 32*kh + 16*(j>>2) + 4*g + (j&3);  // L1-acc perm
                a[j]  = (f16)w1[pg*4096 + k1*64 + 16*mt + u];
                bq[j] = (f16)w2[pg*4096 + k2*64 + 16*mt + u];
            }
            wfA[mt][kh] = a; wfB[mt][kh] = bq;
        }
    f16x8 w0r[2], b0r[2];
    #pragma unroll
    for (int kh = 0; kh < 2; ++kh) {
        f16x8 a, bq;
        #pragma unroll
        for (int j = 0; j < 8; ++j) {
            a[j]  = (f16)w0[pg*64 + 32*kh + 8*g + j];
            bq[j] = (f16)b0[pg*64 + 32*kh + 8*g + j];
        }
        w0r[kh] = a; b0r[kh] = bq;
    }
    f32x4 bv1[4], bv2[4], w3v[4];
    #pragma unroll
    for (int mt = 0; mt < 4; ++mt) {
        bv1[mt] = *(const f32x4*)&b1[pg*64 + 16*mt + 4*g];
        bv2[mt] = *(const f32x4*)&b2[pg*64 + 16*mt + 4*g];
        w3v[mt] = *(const f32x4*)&w3[pg*64 + 16*mt + 4*g];
    }

    float th[4];
    #pragma unroll
    for (int nt = 0; nt < 4; ++nt) th[nt] = __shfl(theta, 16*nt + u);

    // ---- layer 0 -> B-fragments (packed f16)
    f16x8 bf[4][2];
    #pragma unroll
    for (int nt = 0; nt < 4; ++nt) {
        const f16 thh = (f16)th[nt];
        const f16x2 th2 = {thh, thh};
        #pragma unroll
        for (int kh = 0; kh < 2; ++kh) {
            union { f16x2 h2[4]; f16x8 v8; } uu;
            union { f16x8 v8; f16x2 h2[4]; } wv, bv_;
            wv.v8 = w0r[kh]; bv_.v8 = b0r[kh];
            #pragma unroll
            for (int q = 0; q < 4; ++q)
                uu.h2[q] = hmax2(__builtin_elementwise_fma(th2, wv.h2[q], bv_.h2[q]));
            bf[nt][kh] = uu.v8;
        }
    }

    // ---- layer 1 + in-lane repack (perm matches wfB's k-order)
    f16x8 cf[4][2];
    #pragma unroll
    for (int mp = 0; mp < 2; ++mp) {
        f32x4 acc[2][4];
        #pragma unroll
        for (int mh = 0; mh < 2; ++mh) {
            const int mt = 2*mp + mh;
            #pragma unroll
            for (int nt = 0; nt < 4; ++nt) {
                f32x4 a = __builtin_amdgcn_mfma_f32_16x16x32_f16(wfA[mt][0], bf[nt][0], bv1[mt], 0,0,0);
                a = __builtin_amdgcn_mfma_f32_16x16x32_f16(wfA[mt][1], bf[nt][1], a, 0,0,0);
                acc[mh][nt] = a;
            }
        }
        #pragma unroll
        for (int nt = 0; nt < 4; ++nt) {
            union { f16x2 h2[4]; f16x8 v8; } uu;
            #pragma unroll
            for (int hh = 0; hh < 2; ++hh) {
                const f32x4 av = acc[hh][nt];
                uu.h2[hh*2+0] = hmax2(cvt2(av[0], av[1]));
                uu.h2[hh*2+1] = hmax2(cvt2(av[2], av[3]));
            }
            cf[nt][mp] = uu.v8;
        }
    }

    // ---- layer 2 + head
    f32x2 hp2[4] = {{0.f,0.f},{0.f,0.f},{0.f,0.f},{0.f,0.f}};
    #pragma unroll
    for (int mt = 0; mt < 4; ++mt) {
        const f32x2 w301 = {w3v[mt][0], w3v[mt][1]}, w323 = {w3v[mt][2], w3v[mt][3]};
        #pragma unroll
        for (int nt = 0; nt < 4; ++nt) {
            f32x4 a = __builtin_amdgcn_mfma_f32_16x16x32_f16(wfB[mt][0], cf[nt][0], bv2[mt], 0,0,0);
            a = __builtin_amdgcn_mfma_f32_16x16x32_f16(wfB[mt][1], cf[nt][1], a, 0,0,0);
            f32x2 e01 = pmax2((f32x2){a[0], a[1]});
            f32x2 e23 = pmax2((f32x2){a[2], a[3]});
            hp2[nt] = e01*w301 + hp2[nt];
            hp2[nt] = e23*w323 + hp2[nt];
        }
    }
    float hp[4];
    #pragma unroll
    for (int nt = 0; nt < 4; ++nt) {
        hp[nt] = hp2[nt][0] + hp2[nt][1];
        hp[nt] += __shfl_xor(hp[nt], 16);
        hp[nt] += __shfl_xor(hp[nt], 32);
    }
    float ov = hp[0];
    if (g == 1) ov = hp[1];
    if (g == 2) ov = hp[2];
    if (g == 3) ov = hp[3];

    wsf[10752 + pg*TT + i0] = ov + b3[pg];
}

// Render: 1 thread = 4 consecutive pixels (one quad). theta -> table lerp ->
// logit -> sigmoid. scv/pid loads amortized x4; f32x4 coalesced store.
__global__ __launch_bounds__(256) void render_kernel(
    const int* __restrict__ program_id,
    const float* __restrict__ wsf,
    float* __restrict__ out)
{
    const float* tab = wsf + 10752;
    const int gi = blockIdx.x * 256 + threadIdx.x;   // quad index [0, 256K)
    const int b    = gi >> 10;
    const int p4   = gi & 1023;
    const int row  = p4 >> 4;
    const int col0 = (p4 & 15) << 2;
    const float cy = -1.f + (2.f/63.f)*(float)row;

    const f32x4 scv0 = *(const f32x4*)&wsf[8320 + (b*2 + 0)*4];
    const f32x4 scv1 = *(const f32x4*)&wsf[8320 + (b*2 + 1)*4];
    const int   pid  = program_id[b];

    f32x4 res;
    #pragma unroll
    for (int k = 0; k < 4; ++k) {
        const float cx = -1.f + (2.f/63.f)*(float)(col0 + k);
        float p01[2];
        #pragma unroll
        for (int s = 0; s < 2; ++s) {
            const f32x4 scv = s ? scv1 : scv0;
            const float dx = cx - scv[0], dy = cy - scv[1];
            const float theta = fast_atan2(dy, dx);
            const float r2 = sqrtf(dx*dx + dy*dy);
            float x = (theta + PI_F) * ((float)(TT-1)/(2.f*PI_F));
            x = fminf(fmaxf(x, 0.f), (float)(TT-1));
            const float fi = floorf(fminf(x, (float)(TT-2)));
            const int   i  = (int)fi;
            const float f  = x - fi;
            const float* tb = tab + ((int)scv[3])*TT;
            const float t0 = tb[i], t1 = tb[i+1];
            const float o  = fmaf(f, t1 - t0, t0);
            const float logit = scv[2] * (__expf(o) - r2);
            p01[s] = __builtin_amdgcn_rcpf(1.f + __expf(-logit));
        }
        float r;
        if (pid == 0) {
            r = p01[0];
        } else {
            float c = (pid == 2) ? (p01[0] - p01[1]) : (p01[0] + p01[1]);
            r = fminf(fmaxf(c, 0.f), 1.f);
        }
        res[k] = r;
    }
    *(f32x4*)&out[b*(IM*IM) + row*64 + col0] = res;
}

extern "C" void kernel_launch(void* const* d_in, const int* in_sizes, int n_in,
                              void* d_out, int out_size, void* d_ws, size_t ws_size,
                              hipStream_t stream) {
    const int*   program_id    = (const int*)  d_in[0];
    const int*   shape_ids     = (const int*)  d_in[1];
    const float* raw_positions = (const float*)d_in[2];
    const float* w0            = (const float*)d_in[3];
    const float* b0            = (const float*)d_in[4];
    const float* w1            = (const float*)d_in[5];
    const float* b1            = (const float*)d_in[6];
    const float* w2            = (const float*)d_in[7];
    const float* b2            = (const float*)d_in[8];
    const float* w3            = (const float*)d_in[9];
    const float* b3            = (const float*)d_in[10];
    const float* lmr           = (const float*)d_in[11];
    float* out = (float*)d_out;
    float* wsf = (float*)d_ws;                // ~58 KB used

    setup_kernel<<<17, 256, 0, stream>>>(w0, b0, w1, b1, w2, b2, w3, b3,
                                         shape_ids, raw_positions, lmr, wsf);

    render_kernel<<<1024, 256, 0, stream>>>(program_id, wsf, out);
}